// Round 11
// baseline (33.787 us; speedup 1.0000x reference)
//
#include <hip/hip_runtime.h>

// KA-conv: out[b,o,h,w] = sum_m P_om(v) / (1+|Q_om(v)|), v = zero-padded patch
// value, m = c*9+ki*3+kj, M=144. ~75.5M rational evals, pure fp32 VALU.
//
// R11: ledger says amortization-per-tap is the lever (R9 1-eval/tap cost
// +8us over R5's 2-eval/tap) and >=4 waves/SIMD is needed (R1). Get both:
// 512-thr block = 2 c-halves x 256 pixel-threads; each pixel-thread owns
// 4 output rows (4 evals per coefficient fetch, two independent pk-pair
// Horner chains per tap); halves combine via 4KB LDS + one barrier.
// Grid 512 x 8 waves = 4096 waves = 4 waves/SIMD. launch_bounds(512,4)
// -> 128 VGPR cap (R8's (512,8) forced 32 VGPR and spilled 345MB).

constexpr int Bn = 4, Cin = 16, Hh = 64, Ww = 64, Oc = 32, Mtot = 144;

typedef float v2f __attribute__((ext_vector_type(2)));

__global__ __launch_bounds__(512, 4)
void ka_conv_kernel(const float* __restrict__ x,
                    const float* __restrict__ nums,
                    const float* __restrict__ denoms,
                    float* __restrict__ out) {
  __shared__ float part[1024];         // half1's 4 row-accs, stride-256 layout

  const int tid  = threadIdx.x;
  const int pix  = tid & 255;          // pixel-slot: 64 cols x 4 rowgroups
  const int half = tid >> 8;           // 0: c=0..7, 1: c=8..15
  const int n    = blockIdx.x;
  const int ht   = n & 3;              // 4 tiles of 16 rows (low bits)
  const int o    = __builtin_amdgcn_readfirstlane((n >> 2) & 31);  // uniform
  const int b    = n >> 7;             // batch

  const int w  = pix & 63;             // lane == output column
  const int rg = pix >> 6;             // rowgroup 0..3
  const int h0 = ht * 16 + rg * 4;     // this thread's 4 rows: h0..h0+3

  // clamped neighbor rows/cols + validity masks (loop-invariant).
  // interior rows h0..h0+3 are always in [0,63]; only halo rows clamp.
  const int  wm  = max(w - 1, 0), wp = min(w + 1, Ww - 1);
  const bool wl  = w > 0, wr = (w + 1) < Ww;
  const int  hT  = max(h0 - 1, 0);         // top halo row (clamped)
  const int  hB  = min(h0 + 4, Hh - 1);    // bottom halo row (clamped)
  const bool htv = h0 > 0, hbv = (h0 + 4) < Hh;
  const bool tl = htv && wl, tr_ = htv && wr;
  const bool bl = hbv && wl, br = hbv && wr;

  v2f accA = {0.f, 0.f};               // rows (h0, h0+1)
  v2f accB = {0.f, 0.f};               // rows (h0+2, h0+3)
  const float* __restrict__ xb   = x + (size_t)b * Cin * Hh * Ww;
  const float* __restrict__ anum = nums   + (size_t)o * Mtot * 6;  // uniform
  const float* __restrict__ bden = denoms + (size_t)o * Mtot * 4;  // uniform

  // one tap: coeff slot t (0..8) of channel c; p0..p3 = column value at the
  // tap's 4 consecutive input rows -> two packed Horner chains (ILP 2).
#define TAP(t, p0, p1, p2, p3) do {                                            \
    const float a0 = pa[(t)*6 + 0], a1 = pa[(t)*6 + 1], a2 = pa[(t)*6 + 2];    \
    const float a3 = pa[(t)*6 + 3], a4 = pa[(t)*6 + 4], a5 = pa[(t)*6 + 5];    \
    const float c1 = pb[(t)*4 + 0], c2 = pb[(t)*4 + 1];                        \
    const float c3 = pb[(t)*4 + 2], c4 = pb[(t)*4 + 3];                        \
    const v2f vA = {(p0), (p1)}, vB = {(p2), (p3)};                            \
    v2f nA = __builtin_elementwise_fma((v2f){a5, a5}, vA, (v2f){a4, a4});      \
    v2f nB = __builtin_elementwise_fma((v2f){a5, a5}, vB, (v2f){a4, a4});      \
    nA = __builtin_elementwise_fma(nA, vA, (v2f){a3, a3});                     \
    nB = __builtin_elementwise_fma(nB, vB, (v2f){a3, a3});                     \
    nA = __builtin_elementwise_fma(nA, vA, (v2f){a2, a2});                     \
    nB = __builtin_elementwise_fma(nB, vB, (v2f){a2, a2});                     \
    nA = __builtin_elementwise_fma(nA, vA, (v2f){a1, a1});                     \
    nB = __builtin_elementwise_fma(nB, vB, (v2f){a1, a1});                     \
    nA = __builtin_elementwise_fma(nA, vA, (v2f){a0, a0});                     \
    nB = __builtin_elementwise_fma(nB, vB, (v2f){a0, a0});                     \
    v2f dA = __builtin_elementwise_fma((v2f){c4, c4}, vA, (v2f){c3, c3});      \
    v2f dB = __builtin_elementwise_fma((v2f){c4, c4}, vB, (v2f){c3, c3});      \
    dA = __builtin_elementwise_fma(dA, vA, (v2f){c2, c2});                     \
    dB = __builtin_elementwise_fma(dB, vB, (v2f){c2, c2});                     \
    dA = __builtin_elementwise_fma(dA, vA, (v2f){c1, c1});                     \
    dB = __builtin_elementwise_fma(dB, vB, (v2f){c1, c1});                     \
    dA = dA * vA;                                                              \
    dB = dB * vB;                                                              \
    const v2f eA = (v2f){1.f, 1.f} + __builtin_elementwise_abs(dA);            \
    const v2f eB = (v2f){1.f, 1.f} + __builtin_elementwise_abs(dB);            \
    const v2f rA = {__builtin_amdgcn_rcpf(eA.x), __builtin_amdgcn_rcpf(eA.y)}; \
    const v2f rB = {__builtin_amdgcn_rcpf(eB.x), __builtin_amdgcn_rcpf(eB.y)}; \
    accA = __builtin_elementwise_fma(nA, rA, accA);                            \
    accB = __builtin_elementwise_fma(nB, rB, accB);                            \
  } while (0)

  const int cBeg = half * (Cin / 2);   // 0 or 8
  #pragma unroll 2
  for (int ci = 0; ci < Cin / 2; ++ci) {
    const int c = cBeg + ci;
    const float* __restrict__ xc = xb + (size_t)c * (Hh * Ww);
    const float* __restrict__ r0 = xc + hT * Ww;          // h0-1 (clamped)
    const float* __restrict__ r1 = xc + h0 * Ww;          // h0
    const float* __restrict__ r2 = xc + (h0 + 1) * Ww;    // h0+1
    const float* __restrict__ r3 = xc + (h0 + 2) * Ww;    // h0+2
    const float* __restrict__ r4 = xc + (h0 + 3) * Ww;    // h0+3
    const float* __restrict__ r5 = xc + hB * Ww;          // h0+4 (clamped)

    // 18 unconditional coalesced loads (6 rows x 3 cols), mask halos to 0
    float x00 = r0[wm], x01 = r0[w], x02 = r0[wp];
    float x10 = r1[wm], x11 = r1[w], x12 = r1[wp];
    float x20 = r2[wm], x21 = r2[w], x22 = r2[wp];
    float x30 = r3[wm], x31 = r3[w], x32 = r3[wp];
    float x40 = r4[wm], x41 = r4[w], x42 = r4[wp];
    float x50 = r5[wm], x51 = r5[w], x52 = r5[wp];
    x00 = tl ? x00 : 0.f;  x01 = htv ? x01 : 0.f;  x02 = tr_ ? x02 : 0.f;
    x10 = wl ? x10 : 0.f;                          x12 = wr  ? x12 : 0.f;
    x20 = wl ? x20 : 0.f;                          x22 = wr  ? x22 : 0.f;
    x30 = wl ? x30 : 0.f;                          x32 = wr  ? x32 : 0.f;
    x40 = wl ? x40 : 0.f;                          x42 = wr  ? x42 : 0.f;
    x50 = bl ? x50 : 0.f;  x51 = hbv ? x51 : 0.f;  x52 = br  ? x52 : 0.f;

    const float* __restrict__ pa = anum + c * 54;   // 9 taps * 6 coeffs
    const float* __restrict__ pb = bden + c * 36;   // 9 taps * 4 coeffs
    // tap(ki,kj) evaluates column kj at input rows ki..ki+3
    TAP(0, x00, x10, x20, x30);  TAP(1, x01, x11, x21, x31);  TAP(2, x02, x12, x22, x32);
    TAP(3, x10, x20, x30, x40);  TAP(4, x11, x21, x31, x41);  TAP(5, x12, x22, x32, x42);
    TAP(6, x20, x30, x40, x50);  TAP(7, x21, x31, x41, x51);  TAP(8, x22, x32, x42, x52);
  }
#undef TAP

  // combine c-halves: half1 -> LDS (stride-256: conflict-free), half0 stores.
  if (half == 1) {
    part[pix]       = accA.x;
    part[pix + 256] = accA.y;
    part[pix + 512] = accB.x;
    part[pix + 768] = accB.y;
  }
  __syncthreads();
  if (half == 0) {
    float* op = out + ((size_t)(b * Oc + o) * Hh + h0) * Ww + w;
    op[0 * Ww] = accA.x + part[pix];
    op[1 * Ww] = accA.y + part[pix + 256];
    op[2 * Ww] = accB.x + part[pix + 512];
    op[3 * Ww] = accB.y + part[pix + 768];
  }
}

extern "C" void kernel_launch(void* const* d_in, const int* in_sizes, int n_in,
                              void* d_out, int out_size, void* d_ws, size_t ws_size,
                              hipStream_t stream) {
  const float* x      = (const float*)d_in[0];
  const float* nums   = (const float*)d_in[1];
  const float* denoms = (const float*)d_in[2];
  float* out          = (float*)d_out;
  // blockIdx = (b*32 + o)*4 + ht   (ht in low bits)
  dim3 grid(Bn * Oc * 4);
  ka_conv_kernel<<<grid, 512, 0, stream>>>(x, nums, denoms, out);
}